// Round 5
// baseline (343.247 us; speedup 1.0000x reference)
//
#include <hip/hip_runtime.h>

#define N_NODES 50000
#define N_EDGES 800000
#define CDIM 100
#define HDIM 200
#define ODIM 100

typedef __bf16 bf16x8 __attribute__((ext_vector_type(8)));
typedef float f32x4 __attribute__((ext_vector_type(4)));
typedef unsigned short ushort_t;

__device__ __forceinline__ unsigned f2bf(float f) {
    unsigned u = __float_as_uint(f);
    u = (u + 0x7FFFu + ((u >> 16) & 1u)) >> 16;
    return u;  // low 16 bits valid
}
__device__ __forceinline__ float bflo(unsigned u) { return __uint_as_float(u << 16); }
__device__ __forceinline__ float bfhi(unsigned u) { return __uint_as_float(u & 0xFFFF0000u); }

// ---------------- CSR build ----------------

__global__ void count_deg(const int* __restrict__ dst, int* __restrict__ deg) {
    int e = blockIdx.x * 256 + threadIdx.x;
    if (e < N_EDGES) atomicAdd(&deg[dst[e]], 1);
}

__global__ __launch_bounds__(1024) void scan_deg(const int* __restrict__ deg,
                                                 int* __restrict__ off,
                                                 int* __restrict__ cursor) {
    const int T = 1024;
    const int PER = 52;  // 13 int4s; 962 threads cover 50000
    int t = threadIdx.x;
    int start = t * PER;
    const int4* deg4 = (const int4*)deg;

    int sum = 0;
    if (start + PER <= N_NODES) {
#pragma unroll
        for (int q = 0; q < PER / 4; ++q) {
            int4 v = deg4[start / 4 + q];
            sum += v.x + v.y + v.z + v.w;
        }
    } else {
        for (int i = start; i < N_NODES; ++i) sum += deg[i];
    }

    __shared__ int ls[T];
    ls[t] = sum;
    __syncthreads();
    for (int o = 1; o < T; o <<= 1) {
        int v = (t >= o) ? ls[t - o] : 0;
        __syncthreads();
        ls[t] += v;
        __syncthreads();
    }
    int run = (t == 0) ? 0 : ls[t - 1];

    if (start + PER <= N_NODES) {
        int4* off4 = (int4*)off;
        int4* cur4 = (int4*)cursor;
#pragma unroll
        for (int q = 0; q < PER / 4; ++q) {
            int4 v = deg4[start / 4 + q];
            int4 o;
            o.x = run;
            o.y = o.x + v.x;
            o.z = o.y + v.y;
            o.w = o.z + v.z;
            run = o.w + v.w;
            off4[start / 4 + q] = o;
            cur4[start / 4 + q] = o;
        }
    } else if (start <= N_NODES) {
        for (int i = start; i < N_NODES; ++i) {
            off[i] = run;
            cursor[i] = run;
            run += deg[i];
        }
        off[N_NODES] = run;
    }
}

__global__ void scatter_edges(const int* __restrict__ src, const int* __restrict__ dst,
                              int* __restrict__ cursor, int* __restrict__ ssrc) {
    int e = blockIdx.x * 256 + threadIdx.x;
    if (e < N_EDGES) {
        int p = atomicAdd(&cursor[dst[e]], 1);
        ssrc[p] = src[e];
    }
}

// ---------------- weight prep: transposed, zero-padded, bf16 ----------------
// W1t[208][128] <- W1[100][200]^T ; W2t[112][256] <- W2[200][100]^T

__global__ void prep_weights(const float* __restrict__ W1, const float* __restrict__ W2,
                             ushort_t* __restrict__ W1t, ushort_t* __restrict__ W2t) {
    int i = blockIdx.x * 256 + threadIdx.x;
    if (i < 208 * 128) {
        int n = i >> 7, k = i & 127;
        float v = (n < HDIM && k < CDIM) ? W1[k * HDIM + n] : 0.f;
        W1t[i] = (ushort_t)f2bf(v);
    } else {
        int j = i - 208 * 128;
        if (j < 112 * 256) {
            int n = j >> 8, k = j & 255;
            float v = (n < ODIM && k < HDIM) ? W2[k * ODIM + n] : 0.f;
            W2t[j] = (ushort_t)f2bf(v);
        }
    }
}

// ---------------- embedding gather -> bf16 rows ----------------

__global__ void gather_emb_bf16(const float4* __restrict__ emb, const int* __restrict__ ids,
                                uint2* __restrict__ h0) {
    int i = blockIdx.x * 256 + threadIdx.x;
    const int TOT = N_NODES * (CDIM / 4);  // 1.25M float4s
    if (i < TOT) {
        int n = i / 25, q = i - n * 25;
        float4 v = emb[(size_t)ids[n] * 25 + q];
        uint2 o;
        o.x = f2bf(v.x) | (f2bf(v.y) << 16);
        o.y = f2bf(v.z) | (f2bf(v.w) << 16);
        h0[i] = o;
    }
}

// ---------------- CSR aggregation over bf16 rows (dim 100), fp32 accum ----------
// 1 wave/node, 50 lanes x 2 cols; 8 independent gathers in flight per iter.
// !BIAS_RELU: write packed bf16 (GEMM input). BIAS_RELU: +bias, relu, write fp32.

template <bool BIAS_RELU>
__global__ __launch_bounds__(256) void agg_bf16(const unsigned* __restrict__ hb,
                                                const int* __restrict__ ssrc,
                                                const int* __restrict__ off,
                                                const float* __restrict__ bias,
                                                unsigned* __restrict__ outb,
                                                float2* __restrict__ outf) {
    int wave = threadIdx.x >> 6;
    int lane = threadIdx.x & 63;
    int n = blockIdx.x * 4 + wave;
    if (n >= N_NODES) return;
    int s0 = off[n], s1 = off[n + 1];
    if (lane >= 50) return;

    float2 a[4];
#pragma unroll
    for (int q = 0; q < 4; ++q) a[q] = make_float2(0.f, 0.f);

    for (int j = s0; j < s1; j += 8) {
        int lim = s1 - j;  // wave-uniform -> scalar branches, no exec masking
#pragma unroll
        for (int q = 0; q < 8; ++q) {
            if (q < lim) {
                unsigned u = hb[(size_t)ssrc[j + q] * 50 + lane];
                a[q & 3].x += bflo(u);
                a[q & 3].y += bfhi(u);
            }
        }
    }
    float rx = (a[0].x + a[1].x) + (a[2].x + a[3].x);
    float ry = (a[0].y + a[1].y) + (a[2].y + a[3].y);
    if (BIAS_RELU) {
        rx = fmaxf(rx + bias[2 * lane], 0.f);
        ry = fmaxf(ry + bias[2 * lane + 1], 0.f);
        outf[(size_t)n * 50 + lane] = make_float2(rx, ry);
    } else {
        outb[(size_t)n * 50 + lane] = f2bf(rx) | (f2bf(ry) << 16);
    }
}

// ---------------- fused MLP: g = relu(A @ W1t^T + b1) @ W2t^T, all bf16 MFMA --------
// A: a1b [N][100] bf16 (50 uints/row). W1t [208][128], W2t [112][256] (zero-padded).
// Block = 256 thr = 4 waves x 16 rows = 64 rows. B-operands straight from global (L2).
// h1 tile lives only in LDS (aliases the As staging buffer, barrier-separated).

__global__ __launch_bounds__(256) void gemm_fused(const unsigned* __restrict__ A4,
                                                  const ushort_t* __restrict__ W1t,
                                                  const float* __restrict__ b1,
                                                  const ushort_t* __restrict__ W2t,
                                                  ushort_t* __restrict__ gb) {
    const int KP1U = 68;   // As row pitch in uints (136 bf16): +4 uints breaks pow2 banks
    const int P2 = 264;    // H1s row pitch in bf16 (200 real + 56 zero-pad + 8)
    __shared__ char smem[64 * P2 * 2];           // 33.8 KB; As phase uses first 17.4 KB
    unsigned* AsU = (unsigned*)smem;             // [64][68] uints
    ushort_t* As = (ushort_t*)smem;              // same, bf16 view (pitch 136)
    ushort_t* H1s = (ushort_t*)smem;             // [64][264] bf16 (after barrier)

    int tid = threadIdx.x, lane = tid & 63, w = tid >> 6;
    int rl = lane & 15, kg = lane >> 4;          // frag row-in-tile, k-group
    int row0 = blockIdx.x * 64;

    // stage A: 64 rows x 64 uints (cols 50..63 zero = bf16 cols 100..127)
    for (int idx = tid; idx < 64 * 64; idx += 256) {
        int r = idx >> 6, kk = idx & 63;
        int row = row0 + r;
        unsigned v = 0;
        if (row < N_NODES && kk < 50) v = A4[(size_t)row * 50 + kk];
        AsU[r * KP1U + kk] = v;
    }
    __syncthreads();

    // ---- stage 1: acc1 = A @ W1t^T ----
    f32x4 acc1[13];
#pragma unroll
    for (int t = 0; t < 13; ++t) acc1[t] = (f32x4){0.f, 0.f, 0.f, 0.f};
#pragma unroll
    for (int k2 = 0; k2 < 4; ++k2) {
        bf16x8 a = *reinterpret_cast<const bf16x8*>(&As[(w * 16 + rl) * 136 + k2 * 32 + kg * 8]);
#pragma unroll
        for (int t = 0; t < 13; ++t) {
            bf16x8 b = *reinterpret_cast<const bf16x8*>(&W1t[(t * 16 + rl) * 128 + k2 * 32 + kg * 8]);
            acc1[t] = __builtin_amdgcn_mfma_f32_16x16x32_bf16(a, b, acc1[t], 0, 0, 0);
        }
    }
    __syncthreads();  // all As reads done; smem becomes H1s

    // zero pad cols 200..263 (read region extends to k=255)
    for (int idx = tid; idx < 64 * 32; idx += 256) {
        int r = idx >> 5, c = idx & 31;
        ((unsigned*)&H1s[r * P2 + 200])[c] = 0;
    }
    // h1 = relu(acc1 + b1) -> bf16 LDS tile
#pragma unroll
    for (int t = 0; t < 13; ++t) {
        int col = t * 16 + rl;
        if (col < HDIM) {
            float bv = b1[col];
#pragma unroll
            for (int i = 0; i < 4; ++i) {
                int r = w * 16 + kg * 4 + i;
                H1s[r * P2 + col] = (ushort_t)f2bf(fmaxf(acc1[t][i] + bv, 0.f));
            }
        }
    }
    __syncthreads();

    // ---- stage 2: acc2 = h1 @ W2t^T ----
    f32x4 acc2[7];
#pragma unroll
    for (int t = 0; t < 7; ++t) acc2[t] = (f32x4){0.f, 0.f, 0.f, 0.f};
#pragma unroll
    for (int k2 = 0; k2 < 8; ++k2) {
        bf16x8 a = *reinterpret_cast<const bf16x8*>(&H1s[(w * 16 + rl) * P2 + k2 * 32 + kg * 8]);
#pragma unroll
        for (int t = 0; t < 7; ++t) {
            bf16x8 b = *reinterpret_cast<const bf16x8*>(&W2t[(t * 16 + rl) * 256 + k2 * 32 + kg * 8]);
            acc2[t] = __builtin_amdgcn_mfma_f32_16x16x32_bf16(a, b, acc2[t], 0, 0, 0);
        }
    }

    // epilogue: D layout col=lane&15, row=(lane>>4)*4+i  [m89]
#pragma unroll
    for (int t = 0; t < 7; ++t) {
        int col = t * 16 + rl;
        if (col < ODIM) {
#pragma unroll
            for (int i = 0; i < 4; ++i) {
                int row = row0 + w * 16 + kg * 4 + i;
                if (row < N_NODES) gb[(size_t)row * ODIM + col] = (ushort_t)f2bf(acc2[t][i]);
            }
        }
    }
}

// ---------------- launch ----------------

extern "C" void kernel_launch(void* const* d_in, const int* in_sizes, int n_in,
                              void* d_out, int out_size, void* d_ws, size_t ws_size,
                              hipStream_t stream) {
    const float* emb = (const float*)d_in[0];
    const float* W1  = (const float*)d_in[1];
    const float* b1  = (const float*)d_in[2];
    const float* W2  = (const float*)d_in[3];
    const float* b2  = (const float*)d_in[4];
    const int* ids   = (const int*)d_in[5];
    const int* esrc  = (const int*)d_in[6];
    const int* edst  = (const int*)d_in[7];
    float* out = (float*)d_out;

    // workspace layout (all 4B-aligned; ~34 MB total)
    ushort_t* h0b = (ushort_t*)d_ws;                    // [N][100] bf16, 10 MB
    ushort_t* a1b = h0b + (size_t)N_NODES * CDIM;       // [N][100] bf16, 10 MB
    ushort_t* gb  = a1b + (size_t)N_NODES * CDIM;       // [N][100] bf16, 10 MB
    ushort_t* W1t = gb + (size_t)N_NODES * ODIM;        // [208][128] bf16
    ushort_t* W2t = W1t + 208 * 128;                    // [112][256] bf16
    int* deg    = (int*)(W2t + 112 * 256);
    int* off    = deg + N_NODES;
    int* cursor = off + (N_NODES + 1);
    int* ssrc   = cursor + N_NODES;                     // 800K ints

    // CSR build (reused by both layers)
    hipMemsetAsync(deg, 0, N_NODES * sizeof(int), stream);
    count_deg<<<(N_EDGES + 255) / 256, 256, 0, stream>>>(edst, deg);
    scan_deg<<<1, 1024, 0, stream>>>(deg, off, cursor);
    scatter_edges<<<(N_EDGES + 255) / 256, 256, 0, stream>>>(esrc, edst, cursor, ssrc);

    // weights -> bf16 transposed padded
    prep_weights<<<(208 * 128 + 112 * 256 + 255) / 256, 256, 0, stream>>>(W1, W2, W1t, W2t);

    // h0 = bf16(emb[ids])
    gather_emb_bf16<<<(N_NODES * 25 + 255) / 256, 256, 0, stream>>>((const float4*)emb, ids,
                                                                    (uint2*)h0b);
    // agg1 = segsum(h0[src])  (bf16 out)
    agg_bf16<false><<<N_NODES / 4, 256, 0, stream>>>((const unsigned*)h0b, ssrc, off,
                                                     nullptr, (unsigned*)a1b, nullptr);
    // g = relu(agg1 @ W1 + b1) @ W2  (h1 never leaves LDS)
    gemm_fused<<<(N_NODES + 63) / 64, 256, 0, stream>>>((const unsigned*)a1b, W1t, b1, W2t, gb);
    // out = relu(segsum(g[src]) + b2)  (fp32 out)
    agg_bf16<true><<<N_NODES / 4, 256, 0, stream>>>((const unsigned*)gb, ssrc, off,
                                                    b2, nullptr, (float2*)out);
}

// Round 6
// 265.438 us; speedup vs baseline: 1.2931x; 1.2931x over previous
//
#include <hip/hip_runtime.h>

#define N_NODES 50000
#define N_EDGES 800000
#define CDIM 100
#define HDIM 200
#define ODIM 100

typedef __bf16 bf16x8 __attribute__((ext_vector_type(8)));
typedef float f32x4 __attribute__((ext_vector_type(4)));
typedef unsigned short ushort_t;

__device__ __forceinline__ unsigned f2bf(float f) {
    unsigned u = __float_as_uint(f);
    u = (u + 0x7FFFu + ((u >> 16) & 1u)) >> 16;
    return u;  // low 16 bits valid
}
__device__ __forceinline__ float bflo(unsigned u) { return __uint_as_float(u << 16); }
__device__ __forceinline__ float bfhi(unsigned u) { return __uint_as_float(u & 0xFFFF0000u); }

// ---------------- CSR build ----------------

__global__ void count_deg(const int* __restrict__ dst, int* __restrict__ deg) {
    int e = blockIdx.x * 256 + threadIdx.x;
    if (e < N_EDGES) atomicAdd(&deg[dst[e]], 1);
}

__global__ __launch_bounds__(1024) void scan_deg(const int* __restrict__ deg,
                                                 int* __restrict__ off,
                                                 int* __restrict__ cursor) {
    const int T = 1024;
    const int PER = 52;  // 13 int4s; 962 threads cover 50000
    int t = threadIdx.x;
    int start = t * PER;
    const int4* deg4 = (const int4*)deg;

    int sum = 0;
    if (start + PER <= N_NODES) {
#pragma unroll
        for (int q = 0; q < PER / 4; ++q) {
            int4 v = deg4[start / 4 + q];
            sum += v.x + v.y + v.z + v.w;
        }
    } else {
        for (int i = start; i < N_NODES; ++i) sum += deg[i];
    }

    __shared__ int ls[T];
    ls[t] = sum;
    __syncthreads();
    for (int o = 1; o < T; o <<= 1) {
        int v = (t >= o) ? ls[t - o] : 0;
        __syncthreads();
        ls[t] += v;
        __syncthreads();
    }
    int run = (t == 0) ? 0 : ls[t - 1];

    if (start + PER <= N_NODES) {
        int4* off4 = (int4*)off;
        int4* cur4 = (int4*)cursor;
#pragma unroll
        for (int q = 0; q < PER / 4; ++q) {
            int4 v = deg4[start / 4 + q];
            int4 o;
            o.x = run;
            o.y = o.x + v.x;
            o.z = o.y + v.y;
            o.w = o.z + v.z;
            run = o.w + v.w;
            off4[start / 4 + q] = o;
            cur4[start / 4 + q] = o;
        }
    } else if (start <= N_NODES) {
        for (int i = start; i < N_NODES; ++i) {
            off[i] = run;
            cursor[i] = run;
            run += deg[i];
        }
        off[N_NODES] = run;
    }
}

__global__ void scatter_edges(const int* __restrict__ src, const int* __restrict__ dst,
                              int* __restrict__ cursor, int* __restrict__ ssrc) {
    int e = blockIdx.x * 256 + threadIdx.x;
    if (e < N_EDGES) {
        int p = atomicAdd(&cursor[dst[e]], 1);
        ssrc[p] = src[e];
    }
}

// ---------------- weight prep: transposed, zero-padded, bf16 ----------------
// W1t[208][128] <- W1[100][200]^T ; W2t[112][256] <- W2[200][100]^T

__global__ void prep_weights(const float* __restrict__ W1, const float* __restrict__ W2,
                             ushort_t* __restrict__ W1t, ushort_t* __restrict__ W2t) {
    int i = blockIdx.x * 256 + threadIdx.x;
    if (i < 208 * 128) {
        int n = i >> 7, k = i & 127;
        float v = (n < HDIM && k < CDIM) ? W1[k * HDIM + n] : 0.f;
        W1t[i] = (ushort_t)f2bf(v);
    } else {
        int j = i - 208 * 128;
        if (j < 112 * 256) {
            int n = j >> 8, k = j & 255;
            float v = (n < ODIM && k < HDIM) ? W2[k * ODIM + n] : 0.f;
            W2t[j] = (ushort_t)f2bf(v);
        }
    }
}

// ---------------- embedding gather -> bf16 rows ----------------

__global__ void gather_emb_bf16(const float4* __restrict__ emb, const int* __restrict__ ids,
                                uint2* __restrict__ h0) {
    int i = blockIdx.x * 256 + threadIdx.x;
    const int TOT = N_NODES * (CDIM / 4);  // 1.25M float4s
    if (i < TOT) {
        int n = i / 25, q = i - n * 25;
        float4 v = emb[(size_t)ids[n] * 25 + q];
        uint2 o;
        o.x = f2bf(v.x) | (f2bf(v.y) << 16);
        o.y = f2bf(v.z) | (f2bf(v.w) << 16);
        h0[i] = o;
    }
}

// ---------------- CSR aggregation over bf16 rows (dim 100), fp32 accum ----------
// 1 wave/node, 50 lanes x 2 cols, 4-deep unconditional ILP (loads in one BB!).
// !BIAS_RELU: write packed bf16 (GEMM input). BIAS_RELU: +bias, relu, write fp32.

template <bool BIAS_RELU>
__global__ __launch_bounds__(256) void agg_bf16(const unsigned* __restrict__ hb,
                                                const int* __restrict__ ssrc,
                                                const int* __restrict__ off,
                                                const float* __restrict__ bias,
                                                unsigned* __restrict__ outb,
                                                float2* __restrict__ outf) {
    int wave = threadIdx.x >> 6;
    int lane = threadIdx.x & 63;
    int n = blockIdx.x * 4 + wave;
    if (n >= N_NODES) return;
    int s0 = off[n], s1 = off[n + 1];
    if (lane >= 50) return;

    float2 a0 = {0.f, 0.f}, a1 = {0.f, 0.f}, a2 = {0.f, 0.f}, a3 = {0.f, 0.f};
    int j = s0;
    for (; j + 3 < s1; j += 4) {
        int r0 = ssrc[j], r1 = ssrc[j + 1], r2 = ssrc[j + 2], r3 = ssrc[j + 3];
        unsigned u0 = hb[(size_t)r0 * 50 + lane];
        unsigned u1 = hb[(size_t)r1 * 50 + lane];
        unsigned u2 = hb[(size_t)r2 * 50 + lane];
        unsigned u3 = hb[(size_t)r3 * 50 + lane];
        a0.x += bflo(u0); a0.y += bfhi(u0);
        a1.x += bflo(u1); a1.y += bfhi(u1);
        a2.x += bflo(u2); a2.y += bfhi(u2);
        a3.x += bflo(u3); a3.y += bfhi(u3);
    }
    {
        int rem = s1 - j;
        if (rem > 0) { unsigned u = hb[(size_t)ssrc[j] * 50 + lane];     a0.x += bflo(u); a0.y += bfhi(u); }
        if (rem > 1) { unsigned u = hb[(size_t)ssrc[j + 1] * 50 + lane]; a1.x += bflo(u); a1.y += bfhi(u); }
        if (rem > 2) { unsigned u = hb[(size_t)ssrc[j + 2] * 50 + lane]; a2.x += bflo(u); a2.y += bfhi(u); }
    }
    float rx = (a0.x + a1.x) + (a2.x + a3.x);
    float ry = (a0.y + a1.y) + (a2.y + a3.y);
    if (BIAS_RELU) {
        rx = fmaxf(rx + bias[2 * lane], 0.f);
        ry = fmaxf(ry + bias[2 * lane + 1], 0.f);
        outf[(size_t)n * 50 + lane] = make_float2(rx, ry);
    } else {
        outb[(size_t)n * 50 + lane] = f2bf(rx) | (f2bf(ry) << 16);
    }
}

// ---------------- fused MLP: g = relu(A @ W1t^T + b1) @ W2t^T, all bf16 MFMA --------
// A: a1b [N][100] bf16 (50 uints/row). W1t [208][128], W2t [112][256] (zero-padded).
// Block = 256 thr = 4 waves x 16 rows = 64 rows. B-operands straight from global (L2).
// h1 tile lives only in LDS (aliases the As staging buffer, barrier-separated).

__global__ __launch_bounds__(256) void gemm_fused(const unsigned* __restrict__ A4,
                                                  const ushort_t* __restrict__ W1t,
                                                  const float* __restrict__ b1,
                                                  const ushort_t* __restrict__ W2t,
                                                  ushort_t* __restrict__ gb) {
    const int KP1U = 68;   // As row pitch in uints (136 bf16): +4 uints breaks pow2 banks
    const int P2 = 264;    // H1s row pitch in bf16 (200 real + 56 zero-pad + 8)
    __shared__ char smem[64 * P2 * 2];           // 33.8 KB; As phase uses first 17.4 KB
    unsigned* AsU = (unsigned*)smem;             // [64][68] uints
    ushort_t* As = (ushort_t*)smem;              // same, bf16 view (pitch 136)
    ushort_t* H1s = (ushort_t*)smem;             // [64][264] bf16 (after barrier)

    int tid = threadIdx.x, lane = tid & 63, w = tid >> 6;
    int rl = lane & 15, kg = lane >> 4;          // frag row-in-tile, k-group
    int row0 = blockIdx.x * 64;

    // stage A: 64 rows x 64 uints (cols 50..63 zero = bf16 cols 100..127)
    for (int idx = tid; idx < 64 * 64; idx += 256) {
        int r = idx >> 6, kk = idx & 63;
        int row = row0 + r;
        unsigned v = 0;
        if (row < N_NODES && kk < 50) v = A4[(size_t)row * 50 + kk];
        AsU[r * KP1U + kk] = v;
    }
    __syncthreads();

    // ---- stage 1: acc1 = A @ W1t^T ----
    f32x4 acc1[13];
#pragma unroll
    for (int t = 0; t < 13; ++t) acc1[t] = (f32x4){0.f, 0.f, 0.f, 0.f};
#pragma unroll
    for (int k2 = 0; k2 < 4; ++k2) {
        bf16x8 a = *reinterpret_cast<const bf16x8*>(&As[(w * 16 + rl) * 136 + k2 * 32 + kg * 8]);
#pragma unroll
        for (int t = 0; t < 13; ++t) {
            bf16x8 b = *reinterpret_cast<const bf16x8*>(&W1t[(t * 16 + rl) * 128 + k2 * 32 + kg * 8]);
            acc1[t] = __builtin_amdgcn_mfma_f32_16x16x32_bf16(a, b, acc1[t], 0, 0, 0);
        }
    }
    __syncthreads();  // all As reads done; smem becomes H1s

    // zero pad cols 200..263 (read region extends to k=255)
    for (int idx = tid; idx < 64 * 32; idx += 256) {
        int r = idx >> 5, c = idx & 31;
        ((unsigned*)&H1s[r * P2 + 200])[c] = 0;
    }
    // h1 = relu(acc1 + b1) -> bf16 LDS tile
#pragma unroll
    for (int t = 0; t < 13; ++t) {
        int col = t * 16 + rl;
        if (col < HDIM) {
            float bv = b1[col];
#pragma unroll
            for (int i = 0; i < 4; ++i) {
                int r = w * 16 + kg * 4 + i;
                H1s[r * P2 + col] = (ushort_t)f2bf(fmaxf(acc1[t][i] + bv, 0.f));
            }
        }
    }
    __syncthreads();

    // ---- stage 2: acc2 = h1 @ W2t^T ----
    f32x4 acc2[7];
#pragma unroll
    for (int t = 0; t < 7; ++t) acc2[t] = (f32x4){0.f, 0.f, 0.f, 0.f};
#pragma unroll
    for (int k2 = 0; k2 < 8; ++k2) {
        bf16x8 a = *reinterpret_cast<const bf16x8*>(&H1s[(w * 16 + rl) * P2 + k2 * 32 + kg * 8]);
#pragma unroll
        for (int t = 0; t < 7; ++t) {
            bf16x8 b = *reinterpret_cast<const bf16x8*>(&W2t[(t * 16 + rl) * 256 + k2 * 32 + kg * 8]);
            acc2[t] = __builtin_amdgcn_mfma_f32_16x16x32_bf16(a, b, acc2[t], 0, 0, 0);
        }
    }

    // epilogue: D layout col=lane&15, row=(lane>>4)*4+i  [m89]
#pragma unroll
    for (int t = 0; t < 7; ++t) {
        int col = t * 16 + rl;
        if (col < ODIM) {
#pragma unroll
            for (int i = 0; i < 4; ++i) {
                int row = row0 + w * 16 + kg * 4 + i;
                if (row < N_NODES) gb[(size_t)row * ODIM + col] = (ushort_t)f2bf(acc2[t][i]);
            }
        }
    }
}

// ---------------- launch ----------------

extern "C" void kernel_launch(void* const* d_in, const int* in_sizes, int n_in,
                              void* d_out, int out_size, void* d_ws, size_t ws_size,
                              hipStream_t stream) {
    const float* emb = (const float*)d_in[0];
    const float* W1  = (const float*)d_in[1];
    const float* b1  = (const float*)d_in[2];
    const float* W2  = (const float*)d_in[3];
    const float* b2  = (const float*)d_in[4];
    const int* ids   = (const int*)d_in[5];
    const int* esrc  = (const int*)d_in[6];
    const int* edst  = (const int*)d_in[7];
    float* out = (float*)d_out;

    // workspace layout (all 4B-aligned; ~34 MB total)
    ushort_t* h0b = (ushort_t*)d_ws;                    // [N][100] bf16, 10 MB
    ushort_t* a1b = h0b + (size_t)N_NODES * CDIM;       // [N][100] bf16, 10 MB
    ushort_t* gb  = a1b + (size_t)N_NODES * CDIM;       // [N][100] bf16, 10 MB
    ushort_t* W1t = gb + (size_t)N_NODES * ODIM;        // [208][128] bf16
    ushort_t* W2t = W1t + 208 * 128;                    // [112][256] bf16
    int* deg    = (int*)(W2t + 112 * 256);
    int* off    = deg + N_NODES;
    int* cursor = off + (N_NODES + 1);
    int* ssrc   = cursor + N_NODES;                     // 800K ints

    // CSR build (reused by both layers)
    hipMemsetAsync(deg, 0, N_NODES * sizeof(int), stream);
    count_deg<<<(N_EDGES + 255) / 256, 256, 0, stream>>>(edst, deg);
    scan_deg<<<1, 1024, 0, stream>>>(deg, off, cursor);
    scatter_edges<<<(N_EDGES + 255) / 256, 256, 0, stream>>>(esrc, edst, cursor, ssrc);

    // weights -> bf16 transposed padded
    prep_weights<<<(208 * 128 + 112 * 256 + 255) / 256, 256, 0, stream>>>(W1, W2, W1t, W2t);

    // h0 = bf16(emb[ids])
    gather_emb_bf16<<<(N_NODES * 25 + 255) / 256, 256, 0, stream>>>((const float4*)emb, ids,
                                                                    (uint2*)h0b);
    // agg1 = segsum(h0[src])  (bf16 out)
    agg_bf16<false><<<N_NODES / 4, 256, 0, stream>>>((const unsigned*)h0b, ssrc, off,
                                                     nullptr, (unsigned*)a1b, nullptr);
    // g = relu(agg1 @ W1 + b1) @ W2  (h1 never leaves LDS)
    gemm_fused<<<(N_NODES + 63) / 64, 256, 0, stream>>>((const unsigned*)a1b, W1t, b1, W2t, gb);
    // out = relu(segsum(g[src]) + b2)  (fp32 out)
    agg_bf16<true><<<N_NODES / 4, 256, 0, stream>>>((const unsigned*)gb, ssrc, off,
                                                    b2, nullptr, (float2*)out);
}

// Round 7
// 251.879 us; speedup vs baseline: 1.3627x; 1.0538x over previous
//
#include <hip/hip_runtime.h>

#define N_NODES 50000
#define N_EDGES 800000
#define CDIM 100
#define HDIM 200
#define ODIM 100

typedef __bf16 bf16x8 __attribute__((ext_vector_type(8)));
typedef float f32x4 __attribute__((ext_vector_type(4)));
typedef unsigned short ushort_t;

__device__ __forceinline__ unsigned f2bf(float f) {
    unsigned u = __float_as_uint(f);
    u = (u + 0x7FFFu + ((u >> 16) & 1u)) >> 16;
    return u;  // low 16 bits valid
}
__device__ __forceinline__ float bflo(unsigned u) { return __uint_as_float(u << 16); }
__device__ __forceinline__ float bfhi(unsigned u) { return __uint_as_float(u & 0xFFFF0000u); }

// ---------------- CSR build ----------------

__global__ void count_deg(const int* __restrict__ dst, int* __restrict__ deg) {
    int e = blockIdx.x * 256 + threadIdx.x;
    if (e < N_EDGES) atomicAdd(&deg[dst[e]], 1);
}

__global__ __launch_bounds__(1024) void scan_deg(const int* __restrict__ deg,
                                                 int* __restrict__ off,
                                                 int* __restrict__ cursor) {
    const int T = 1024;
    const int PER = 52;  // 13 int4s; 962 threads cover 50000
    int t = threadIdx.x;
    int start = t * PER;
    const int4* deg4 = (const int4*)deg;

    int sum = 0;
    if (start + PER <= N_NODES) {
#pragma unroll
        for (int q = 0; q < PER / 4; ++q) {
            int4 v = deg4[start / 4 + q];
            sum += v.x + v.y + v.z + v.w;
        }
    } else {
        for (int i = start; i < N_NODES; ++i) sum += deg[i];
    }

    __shared__ int ls[T];
    ls[t] = sum;
    __syncthreads();
    for (int o = 1; o < T; o <<= 1) {
        int v = (t >= o) ? ls[t - o] : 0;
        __syncthreads();
        ls[t] += v;
        __syncthreads();
    }
    int run = (t == 0) ? 0 : ls[t - 1];

    if (start + PER <= N_NODES) {
        int4* off4 = (int4*)off;
        int4* cur4 = (int4*)cursor;
#pragma unroll
        for (int q = 0; q < PER / 4; ++q) {
            int4 v = deg4[start / 4 + q];
            int4 o;
            o.x = run;
            o.y = o.x + v.x;
            o.z = o.y + v.y;
            o.w = o.z + v.z;
            run = o.w + v.w;
            off4[start / 4 + q] = o;
            cur4[start / 4 + q] = o;
        }
    } else if (start <= N_NODES) {
        for (int i = start; i < N_NODES; ++i) {
            off[i] = run;
            cursor[i] = run;
            run += deg[i];
        }
        off[N_NODES] = run;
    }
}

// ---------------- fused independent stage: scatter | gather | weight-prep ----------
// blocks [0,3125): scatter edges into CSR slots
// blocks [3125,8008): h0 = bf16(emb[ids])
// blocks [8008,8224): W1t[208][128] <- bf16(W1^T) zero-pad; W2t[112][256] <- bf16(W2^T)

__global__ __launch_bounds__(256) void scatter_gather_prep(
    const int* __restrict__ esrc, const int* __restrict__ edst,
    int* __restrict__ cursor, int* __restrict__ ssrc,
    const float4* __restrict__ emb, const int* __restrict__ ids, uint2* __restrict__ h0,
    const float* __restrict__ W1, const float* __restrict__ W2,
    ushort_t* __restrict__ W1t, ushort_t* __restrict__ W2t) {
    int b = blockIdx.x;
    if (b < 3125) {
        int e = b * 256 + threadIdx.x;
        if (e < N_EDGES) {
            int p = atomicAdd(&cursor[edst[e]], 1);
            ssrc[p] = esrc[e];
        }
    } else if (b < 8008) {
        int i = (b - 3125) * 256 + threadIdx.x;
        const int TOT = N_NODES * 25;  // 1.25M float4s
        if (i < TOT) {
            int n = i / 25, q = i - n * 25;
            float4 v = emb[(size_t)ids[n] * 25 + q];
            uint2 o;
            o.x = f2bf(v.x) | (f2bf(v.y) << 16);
            o.y = f2bf(v.z) | (f2bf(v.w) << 16);
            h0[i] = o;
        }
    } else {
        int i = (b - 8008) * 256 + threadIdx.x;
        if (i < 208 * 128) {
            int n = i >> 7, k = i & 127;
            float v = (n < HDIM && k < CDIM) ? W1[k * HDIM + n] : 0.f;
            W1t[i] = (ushort_t)f2bf(v);
        } else {
            int j = i - 208 * 128;
            if (j < 112 * 256) {
                int n = j >> 8, k = j & 255;
                float v = (n < ODIM && k < HDIM) ? W2[k * ODIM + n] : 0.f;
                W2t[j] = (ushort_t)f2bf(v);
            }
        }
    }
}

// ---------------- CSR aggregation over bf16 rows (dim 100), fp32 accum ----------
// 1 wave/node, 50 lanes x 2 cols; 8-deep unconditional ILP main loop, then 4, then tail.
// !BIAS_RELU: write packed bf16 (GEMM input). BIAS_RELU: +bias, relu, write fp32.

template <bool BIAS_RELU>
__global__ __launch_bounds__(256) void agg_bf16(const unsigned* __restrict__ hb,
                                                const int* __restrict__ ssrc,
                                                const int* __restrict__ off,
                                                const float* __restrict__ bias,
                                                unsigned* __restrict__ outb,
                                                float2* __restrict__ outf) {
    int wave = threadIdx.x >> 6;
    int lane = threadIdx.x & 63;
    int n = blockIdx.x * 4 + wave;
    if (n >= N_NODES) return;
    int s0 = off[n], s1 = off[n + 1];
    if (lane >= 50) return;

    float2 a0 = {0.f, 0.f}, a1 = {0.f, 0.f}, a2 = {0.f, 0.f}, a3 = {0.f, 0.f};
    int j = s0;
    for (; j + 7 < s1; j += 8) {
        int r0 = ssrc[j],     r1 = ssrc[j + 1], r2 = ssrc[j + 2], r3 = ssrc[j + 3];
        int r4 = ssrc[j + 4], r5 = ssrc[j + 5], r6 = ssrc[j + 6], r7 = ssrc[j + 7];
        unsigned u0 = hb[(size_t)r0 * 50 + lane];
        unsigned u1 = hb[(size_t)r1 * 50 + lane];
        unsigned u2 = hb[(size_t)r2 * 50 + lane];
        unsigned u3 = hb[(size_t)r3 * 50 + lane];
        unsigned u4 = hb[(size_t)r4 * 50 + lane];
        unsigned u5 = hb[(size_t)r5 * 50 + lane];
        unsigned u6 = hb[(size_t)r6 * 50 + lane];
        unsigned u7 = hb[(size_t)r7 * 50 + lane];
        a0.x += bflo(u0); a0.y += bfhi(u0);
        a1.x += bflo(u1); a1.y += bfhi(u1);
        a2.x += bflo(u2); a2.y += bfhi(u2);
        a3.x += bflo(u3); a3.y += bfhi(u3);
        a0.x += bflo(u4); a0.y += bfhi(u4);
        a1.x += bflo(u5); a1.y += bfhi(u5);
        a2.x += bflo(u6); a2.y += bfhi(u6);
        a3.x += bflo(u7); a3.y += bfhi(u7);
    }
    for (; j + 3 < s1; j += 4) {
        int r0 = ssrc[j], r1 = ssrc[j + 1], r2 = ssrc[j + 2], r3 = ssrc[j + 3];
        unsigned u0 = hb[(size_t)r0 * 50 + lane];
        unsigned u1 = hb[(size_t)r1 * 50 + lane];
        unsigned u2 = hb[(size_t)r2 * 50 + lane];
        unsigned u3 = hb[(size_t)r3 * 50 + lane];
        a0.x += bflo(u0); a0.y += bfhi(u0);
        a1.x += bflo(u1); a1.y += bfhi(u1);
        a2.x += bflo(u2); a2.y += bfhi(u2);
        a3.x += bflo(u3); a3.y += bfhi(u3);
    }
    {
        int rem = s1 - j;
        if (rem > 0) { unsigned u = hb[(size_t)ssrc[j] * 50 + lane];     a0.x += bflo(u); a0.y += bfhi(u); }
        if (rem > 1) { unsigned u = hb[(size_t)ssrc[j + 1] * 50 + lane]; a1.x += bflo(u); a1.y += bfhi(u); }
        if (rem > 2) { unsigned u = hb[(size_t)ssrc[j + 2] * 50 + lane]; a2.x += bflo(u); a2.y += bfhi(u); }
    }
    float rx = (a0.x + a1.x) + (a2.x + a3.x);
    float ry = (a0.y + a1.y) + (a2.y + a3.y);
    if (BIAS_RELU) {
        rx = fmaxf(rx + bias[2 * lane], 0.f);
        ry = fmaxf(ry + bias[2 * lane + 1], 0.f);
        outf[(size_t)n * 50 + lane] = make_float2(rx, ry);
    } else {
        outb[(size_t)n * 50 + lane] = f2bf(rx) | (f2bf(ry) << 16);
    }
}

// ---------------- fused MLP: g = relu(A @ W1t^T + b1) @ W2t^T, all bf16 MFMA --------
// A: a1b [N][100] bf16 (50 uints/row). W1t [208][128], W2t [112][256] (zero-padded).
// Block = 256 thr = 4 waves x 16 rows = 64 rows. B-operands straight from global (L2).
// h1 tile lives only in LDS (aliases the As staging buffer, barrier-separated).

__global__ __launch_bounds__(256) void gemm_fused(const unsigned* __restrict__ A4,
                                                  const ushort_t* __restrict__ W1t,
                                                  const float* __restrict__ b1,
                                                  const ushort_t* __restrict__ W2t,
                                                  ushort_t* __restrict__ gb) {
    const int KP1U = 68;   // As row pitch in uints (136 bf16): +4 uints breaks pow2 banks
    const int P2 = 264;    // H1s row pitch in bf16 (200 real + 56 zero-pad + 8)
    __shared__ char smem[64 * P2 * 2];           // 33.8 KB; As phase uses first 17.4 KB
    unsigned* AsU = (unsigned*)smem;             // [64][68] uints
    ushort_t* As = (ushort_t*)smem;              // same, bf16 view (pitch 136)
    ushort_t* H1s = (ushort_t*)smem;             // [64][264] bf16 (after barrier)

    int tid = threadIdx.x, lane = tid & 63, w = tid >> 6;
    int rl = lane & 15, kg = lane >> 4;          // frag row-in-tile, k-group
    int row0 = blockIdx.x * 64;

    // stage A: 64 rows x 64 uints (cols 50..63 zero = bf16 cols 100..127)
    for (int idx = tid; idx < 64 * 64; idx += 256) {
        int r = idx >> 6, kk = idx & 63;
        int row = row0 + r;
        unsigned v = 0;
        if (row < N_NODES && kk < 50) v = A4[(size_t)row * 50 + kk];
        AsU[r * KP1U + kk] = v;
    }
    __syncthreads();

    // ---- stage 1: acc1 = A @ W1t^T ----
    f32x4 acc1[13];
#pragma unroll
    for (int t = 0; t < 13; ++t) acc1[t] = (f32x4){0.f, 0.f, 0.f, 0.f};
#pragma unroll
    for (int k2 = 0; k2 < 4; ++k2) {
        bf16x8 a = *reinterpret_cast<const bf16x8*>(&As[(w * 16 + rl) * 136 + k2 * 32 + kg * 8]);
#pragma unroll
        for (int t = 0; t < 13; ++t) {
            bf16x8 b = *reinterpret_cast<const bf16x8*>(&W1t[(t * 16 + rl) * 128 + k2 * 32 + kg * 8]);
            acc1[t] = __builtin_amdgcn_mfma_f32_16x16x32_bf16(a, b, acc1[t], 0, 0, 0);
        }
    }
    __syncthreads();  // all As reads done; smem becomes H1s

    // zero pad cols 200..263 (read region extends to k=255)
    for (int idx = tid; idx < 64 * 32; idx += 256) {
        int r = idx >> 5, c = idx & 31;
        ((unsigned*)&H1s[r * P2 + 200])[c] = 0;
    }
    // h1 = relu(acc1 + b1) -> bf16 LDS tile
#pragma unroll
    for (int t = 0; t < 13; ++t) {
        int col = t * 16 + rl;
        if (col < HDIM) {
            float bv = b1[col];
#pragma unroll
            for (int i = 0; i < 4; ++i) {
                int r = w * 16 + kg * 4 + i;
                H1s[r * P2 + col] = (ushort_t)f2bf(fmaxf(acc1[t][i] + bv, 0.f));
            }
        }
    }
    __syncthreads();

    // ---- stage 2: acc2 = h1 @ W2t^T ----
    f32x4 acc2[7];
#pragma unroll
    for (int t = 0; t < 7; ++t) acc2[t] = (f32x4){0.f, 0.f, 0.f, 0.f};
#pragma unroll
    for (int k2 = 0; k2 < 8; ++k2) {
        bf16x8 a = *reinterpret_cast<const bf16x8*>(&H1s[(w * 16 + rl) * P2 + k2 * 32 + kg * 8]);
#pragma unroll
        for (int t = 0; t < 7; ++t) {
            bf16x8 b = *reinterpret_cast<const bf16x8*>(&W2t[(t * 16 + rl) * 256 + k2 * 32 + kg * 8]);
            acc2[t] = __builtin_amdgcn_mfma_f32_16x16x32_bf16(a, b, acc2[t], 0, 0, 0);
        }
    }

    // epilogue: D layout col=lane&15, row=(lane>>4)*4+i  [m89]
#pragma unroll
    for (int t = 0; t < 7; ++t) {
        int col = t * 16 + rl;
        if (col < ODIM) {
#pragma unroll
            for (int i = 0; i < 4; ++i) {
                int row = row0 + w * 16 + kg * 4 + i;
                if (row < N_NODES) gb[(size_t)row * ODIM + col] = (ushort_t)f2bf(acc2[t][i]);
            }
        }
    }
}

// ---------------- launch ----------------

extern "C" void kernel_launch(void* const* d_in, const int* in_sizes, int n_in,
                              void* d_out, int out_size, void* d_ws, size_t ws_size,
                              hipStream_t stream) {
    const float* emb = (const float*)d_in[0];
    const float* W1  = (const float*)d_in[1];
    const float* b1  = (const float*)d_in[2];
    const float* W2  = (const float*)d_in[3];
    const float* b2  = (const float*)d_in[4];
    const int* ids   = (const int*)d_in[5];
    const int* esrc  = (const int*)d_in[6];
    const int* edst  = (const int*)d_in[7];
    float* out = (float*)d_out;

    // workspace layout (all 4B-aligned; ~34 MB total)
    ushort_t* h0b = (ushort_t*)d_ws;                    // [N][100] bf16, 10 MB
    ushort_t* a1b = h0b + (size_t)N_NODES * CDIM;       // [N][100] bf16, 10 MB
    ushort_t* gb  = a1b + (size_t)N_NODES * CDIM;       // [N][100] bf16, 10 MB
    ushort_t* W1t = gb + (size_t)N_NODES * ODIM;        // [208][128] bf16
    ushort_t* W2t = W1t + 208 * 128;                    // [112][256] bf16
    int* deg    = (int*)(W2t + 112 * 256);
    int* off    = deg + N_NODES;
    int* cursor = off + (N_NODES + 1);
    int* ssrc   = cursor + N_NODES;                     // 800K ints

    // CSR build (reused by both layers)
    hipMemsetAsync(deg, 0, N_NODES * sizeof(int), stream);
    count_deg<<<(N_EDGES + 255) / 256, 256, 0, stream>>>(edst, deg);
    scan_deg<<<1, 1024, 0, stream>>>(deg, off, cursor);

    // scatter + gather + weight-prep (mutually independent) in one launch
    scatter_gather_prep<<<8224, 256, 0, stream>>>(esrc, edst, cursor, ssrc,
                                                  (const float4*)emb, ids, (uint2*)h0b,
                                                  W1, W2, W1t, W2t);

    // agg1 = segsum(h0[src])  (bf16 out)
    agg_bf16<false><<<N_NODES / 4, 256, 0, stream>>>((const unsigned*)h0b, ssrc, off,
                                                     nullptr, (unsigned*)a1b, nullptr);
    // g = relu(agg1 @ W1 + b1) @ W2  (h1 never leaves LDS)
    gemm_fused<<<(N_NODES + 63) / 64, 256, 0, stream>>>((const unsigned*)a1b, W1t, b1, W2t, gb);
    // out = relu(segsum(g[src]) + b2)  (fp32 out)
    agg_bf16<true><<<N_NODES / 4, 256, 0, stream>>>((const unsigned*)gb, ssrc, off,
                                                    b2, nullptr, (float2*)out);
}

// Round 8
// 250.041 us; speedup vs baseline: 1.3728x; 1.0074x over previous
//
#include <hip/hip_runtime.h>

#define N_NODES 50000
#define N_EDGES 800000
#define CDIM 100
#define HDIM 200
#define ODIM 100

typedef __bf16 bf16x8 __attribute__((ext_vector_type(8)));
typedef float f32x4 __attribute__((ext_vector_type(4)));
typedef unsigned short ushort_t;

__device__ __forceinline__ unsigned f2bf(float f) {
    unsigned u = __float_as_uint(f);
    u = (u + 0x7FFFu + ((u >> 16) & 1u)) >> 16;
    return u;  // low 16 bits valid
}
__device__ __forceinline__ float bflo(unsigned u) { return __uint_as_float(u << 16); }
__device__ __forceinline__ float bfhi(unsigned u) { return __uint_as_float(u & 0xFFFF0000u); }

// Node-feature tables use pitch 128 bf16 = 64 uints = 256 B (2 cache lines, aligned).
#define PITCH_U 64

// ---------------- CSR build ----------------

__global__ void count_deg(const int* __restrict__ dst, int* __restrict__ deg) {
    int e = blockIdx.x * 256 + threadIdx.x;
    if (e < N_EDGES) atomicAdd(&deg[dst[e]], 1);
}

__global__ __launch_bounds__(1024) void scan_deg(const int* __restrict__ deg,
                                                 int* __restrict__ off,
                                                 int* __restrict__ cursor) {
    const int T = 1024;
    const int PER = 52;  // 13 int4s; 962 threads cover 50000
    int t = threadIdx.x;
    int start = t * PER;
    const int4* deg4 = (const int4*)deg;

    int sum = 0;
    if (start + PER <= N_NODES) {
#pragma unroll
        for (int q = 0; q < PER / 4; ++q) {
            int4 v = deg4[start / 4 + q];
            sum += v.x + v.y + v.z + v.w;
        }
    } else {
        for (int i = start; i < N_NODES; ++i) sum += deg[i];
    }

    __shared__ int ls[T];
    ls[t] = sum;
    __syncthreads();
    for (int o = 1; o < T; o <<= 1) {
        int v = (t >= o) ? ls[t - o] : 0;
        __syncthreads();
        ls[t] += v;
        __syncthreads();
    }
    int run = (t == 0) ? 0 : ls[t - 1];

    if (start + PER <= N_NODES) {
        int4* off4 = (int4*)off;
        int4* cur4 = (int4*)cursor;
#pragma unroll
        for (int q = 0; q < PER / 4; ++q) {
            int4 v = deg4[start / 4 + q];
            int4 o;
            o.x = run;
            o.y = o.x + v.x;
            o.z = o.y + v.y;
            o.w = o.z + v.z;
            run = o.w + v.w;
            off4[start / 4 + q] = o;
            cur4[start / 4 + q] = o;
        }
    } else if (start <= N_NODES) {
        for (int i = start; i < N_NODES; ++i) {
            off[i] = run;
            cursor[i] = run;
            run += deg[i];
        }
        off[N_NODES] = run;
    }
}

// ---------------- fused independent stage: scatter | gather | weight-prep ----------
// blocks [0,3125): scatter edges into CSR slots
// blocks [3125,9375): h0 = bf16(emb[ids]) into pitch-256B rows (pad cols zeroed)
// blocks [9375,9591): W1t[208][128] <- bf16(W1^T); W2t[112][256] <- bf16(W2^T)

__global__ __launch_bounds__(256) void scatter_gather_prep(
    const int* __restrict__ esrc, const int* __restrict__ edst,
    int* __restrict__ cursor, int* __restrict__ ssrc,
    const float4* __restrict__ emb, const int* __restrict__ ids, uint2* __restrict__ h0,
    const float* __restrict__ W1, const float* __restrict__ W2,
    ushort_t* __restrict__ W1t, ushort_t* __restrict__ W2t) {
    int b = blockIdx.x;
    if (b < 3125) {
        int e = b * 256 + threadIdx.x;
        if (e < N_EDGES) {
            int p = atomicAdd(&cursor[edst[e]], 1);
            ssrc[p] = esrc[e];
        }
    } else if (b < 9375) {
        int i = (b - 3125) * 256 + threadIdx.x;  // i = n*32 + q (32 uint2 per row)
        const int TOT = N_NODES * 32;            // 1.6M uint2
        if (i < TOT) {
            int n = i >> 5, q = i & 31;
            uint2 o = make_uint2(0u, 0u);
            if (q < 25) {
                float4 v = emb[(size_t)ids[n] * 25 + q];
                o.x = f2bf(v.x) | (f2bf(v.y) << 16);
                o.y = f2bf(v.z) | (f2bf(v.w) << 16);
            }
            h0[i] = o;
        }
    } else {
        int i = (b - 9375) * 256 + threadIdx.x;
        if (i < 208 * 128) {
            int n = i >> 7, k = i & 127;
            float v = (n < HDIM && k < CDIM) ? W1[k * HDIM + n] : 0.f;
            W1t[i] = (ushort_t)f2bf(v);
        } else {
            int j = i - 208 * 128;
            if (j < 112 * 256) {
                int n = j >> 8, k = j & 255;
                float v = (n < ODIM && k < HDIM) ? W2[k * ODIM + n] : 0.f;
                W2t[j] = (ushort_t)f2bf(v);
            }
        }
    }
}

// ---------------- CSR aggregation over pitch-256B bf16 rows, fp32 accum ----------
// 1 wave/node, 64 lanes (lanes 50..63 carry pad zeros); 8-deep unconditional ILP.
// !BIAS_RELU: write packed bf16 pitch-64-uint row (incl. zero pads).
// BIAS_RELU: +bias, relu, write fp32 dense [N][100] (lanes < 50).

template <bool BIAS_RELU>
__global__ __launch_bounds__(256) void agg_bf16(const unsigned* __restrict__ hb,
                                                const int* __restrict__ ssrc,
                                                const int* __restrict__ off,
                                                const float* __restrict__ bias,
                                                unsigned* __restrict__ outb,
                                                float2* __restrict__ outf) {
    int wave = threadIdx.x >> 6;
    int lane = threadIdx.x & 63;
    int n = blockIdx.x * 4 + wave;
    if (n >= N_NODES) return;
    int s0 = off[n], s1 = off[n + 1];

    float2 a0 = {0.f, 0.f}, a1 = {0.f, 0.f}, a2 = {0.f, 0.f}, a3 = {0.f, 0.f};
    int j = s0;
    for (; j + 7 < s1; j += 8) {
        int r0 = ssrc[j],     r1 = ssrc[j + 1], r2 = ssrc[j + 2], r3 = ssrc[j + 3];
        int r4 = ssrc[j + 4], r5 = ssrc[j + 5], r6 = ssrc[j + 6], r7 = ssrc[j + 7];
        unsigned u0 = hb[(size_t)r0 * PITCH_U + lane];
        unsigned u1 = hb[(size_t)r1 * PITCH_U + lane];
        unsigned u2 = hb[(size_t)r2 * PITCH_U + lane];
        unsigned u3 = hb[(size_t)r3 * PITCH_U + lane];
        unsigned u4 = hb[(size_t)r4 * PITCH_U + lane];
        unsigned u5 = hb[(size_t)r5 * PITCH_U + lane];
        unsigned u6 = hb[(size_t)r6 * PITCH_U + lane];
        unsigned u7 = hb[(size_t)r7 * PITCH_U + lane];
        a0.x += bflo(u0); a0.y += bfhi(u0);
        a1.x += bflo(u1); a1.y += bfhi(u1);
        a2.x += bflo(u2); a2.y += bfhi(u2);
        a3.x += bflo(u3); a3.y += bfhi(u3);
        a0.x += bflo(u4); a0.y += bfhi(u4);
        a1.x += bflo(u5); a1.y += bfhi(u5);
        a2.x += bflo(u6); a2.y += bfhi(u6);
        a3.x += bflo(u7); a3.y += bfhi(u7);
    }
    for (; j + 3 < s1; j += 4) {
        int r0 = ssrc[j], r1 = ssrc[j + 1], r2 = ssrc[j + 2], r3 = ssrc[j + 3];
        unsigned u0 = hb[(size_t)r0 * PITCH_U + lane];
        unsigned u1 = hb[(size_t)r1 * PITCH_U + lane];
        unsigned u2 = hb[(size_t)r2 * PITCH_U + lane];
        unsigned u3 = hb[(size_t)r3 * PITCH_U + lane];
        a0.x += bflo(u0); a0.y += bfhi(u0);
        a1.x += bflo(u1); a1.y += bfhi(u1);
        a2.x += bflo(u2); a2.y += bfhi(u2);
        a3.x += bflo(u3); a3.y += bfhi(u3);
    }
    {
        int rem = s1 - j;
        if (rem > 0) { unsigned u = hb[(size_t)ssrc[j] * PITCH_U + lane];     a0.x += bflo(u); a0.y += bfhi(u); }
        if (rem > 1) { unsigned u = hb[(size_t)ssrc[j + 1] * PITCH_U + lane]; a1.x += bflo(u); a1.y += bfhi(u); }
        if (rem > 2) { unsigned u = hb[(size_t)ssrc[j + 2] * PITCH_U + lane]; a2.x += bflo(u); a2.y += bfhi(u); }
    }
    float rx = (a0.x + a1.x) + (a2.x + a3.x);
    float ry = (a0.y + a1.y) + (a2.y + a3.y);
    if (BIAS_RELU) {
        if (lane < 50) {
            rx = fmaxf(rx + bias[2 * lane], 0.f);
            ry = fmaxf(ry + bias[2 * lane + 1], 0.f);
            outf[(size_t)n * 50 + lane] = make_float2(rx, ry);
        }
    } else {
        outb[(size_t)n * PITCH_U + lane] = f2bf(rx) | (f2bf(ry) << 16);
    }
}

// ---------------- fused MLP: g = relu(A @ W1t^T + b1) @ W2t^T, all bf16 MFMA --------
// A: a1b [N][128] bf16 (pitch-256B, zero-padded). W1t [208][128], W2t [112][256].
// Block = 4 waves x 16 rows = 64 rows. Stage-1 A-frags read DIRECTLY from global
// (each element consumed once -> staging is pure overhead). h1 tile lives in LDS only.
// g out: pitch-256B rows, pad cols 100..127 zeroed.

__global__ __launch_bounds__(256) void gemm_fused(const ushort_t* __restrict__ Ab,
                                                  const ushort_t* __restrict__ W1t,
                                                  const float* __restrict__ b1,
                                                  const ushort_t* __restrict__ W2t,
                                                  ushort_t* __restrict__ gb) {
    const int P2 = 264;  // H1s row pitch (bf16): 200 data + 56 zero + 8 slack
    __shared__ ushort_t H1s[64 * P2];  // 33.8 KB

    int tid = threadIdx.x, lane = tid & 63, w = tid >> 6;
    int rl = lane & 15, kg = lane >> 4;
    int row0 = blockIdx.x * 64;

    // ---- stage 1: acc1 = A @ W1t^T (A-frags straight from global; rows OOB-safe) ----
    size_t abase = ((size_t)(row0 + w * 16 + rl)) * 128;
    f32x4 acc1[13];
#pragma unroll
    for (int t = 0; t < 13; ++t) acc1[t] = (f32x4){0.f, 0.f, 0.f, 0.f};
#pragma unroll
    for (int k2 = 0; k2 < 4; ++k2) {
        bf16x8 a = *reinterpret_cast<const bf16x8*>(&Ab[abase + k2 * 32 + kg * 8]);
#pragma unroll
        for (int t = 0; t < 13; ++t) {
            bf16x8 b = *reinterpret_cast<const bf16x8*>(&W1t[(t * 16 + rl) * 128 + k2 * 32 + kg * 8]);
            acc1[t] = __builtin_amdgcn_mfma_f32_16x16x32_bf16(a, b, acc1[t], 0, 0, 0);
        }
    }

    // zero pad cols 200..263
    for (int idx = tid; idx < 64 * 32; idx += 256) {
        int r = idx >> 5, c = idx & 31;
        ((unsigned*)&H1s[r * P2 + 200])[c] = 0;
    }
    // h1 = relu(acc1 + b1) -> bf16 LDS tile (D layout: col=lane&15, row=(lane>>4)*4+i)
#pragma unroll
    for (int t = 0; t < 13; ++t) {
        int col = t * 16 + rl;
        if (col < HDIM) {
            float bv = b1[col];
#pragma unroll
            for (int i = 0; i < 4; ++i) {
                int r = w * 16 + kg * 4 + i;
                H1s[r * P2 + col] = (ushort_t)f2bf(fmaxf(acc1[t][i] + bv, 0.f));
            }
        }
    }
    __syncthreads();

    // ---- stage 2: acc2 = h1 @ W2t^T ----
    f32x4 acc2[7];
#pragma unroll
    for (int t = 0; t < 7; ++t) acc2[t] = (f32x4){0.f, 0.f, 0.f, 0.f};
#pragma unroll
    for (int k2 = 0; k2 < 8; ++k2) {
        bf16x8 a = *reinterpret_cast<const bf16x8*>(&H1s[(w * 16 + rl) * P2 + k2 * 32 + kg * 8]);
#pragma unroll
        for (int t = 0; t < 7; ++t) {
            bf16x8 b = *reinterpret_cast<const bf16x8*>(&W2t[(t * 16 + rl) * 256 + k2 * 32 + kg * 8]);
            acc2[t] = __builtin_amdgcn_mfma_f32_16x16x32_bf16(a, b, acc2[t], 0, 0, 0);
        }
    }

    // epilogue: cols 0..99 = acc2, 100..111 = 0 (t=6 lanes), 112..127 = 0 (extra loop)
#pragma unroll
    for (int t = 0; t < 7; ++t) {
        int col = t * 16 + rl;
#pragma unroll
        for (int i = 0; i < 4; ++i) {
            int row = row0 + w * 16 + kg * 4 + i;
            if (row < N_NODES) {
                float v = (col < ODIM) ? acc2[t][i] : 0.f;
                gb[(size_t)row * 128 + col] = (ushort_t)f2bf(v);
            }
        }
    }
    // zero cols 112..127 (uints 56..63 of each row)
    unsigned* gbu = (unsigned*)gb;
    for (int idx = tid; idx < 64 * 8; idx += 256) {
        int r = idx >> 3, c = idx & 7;
        int row = row0 + r;
        if (row < N_NODES) gbu[(size_t)row * PITCH_U + 56 + c] = 0;
    }
}

// ---------------- launch ----------------

extern "C" void kernel_launch(void* const* d_in, const int* in_sizes, int n_in,
                              void* d_out, int out_size, void* d_ws, size_t ws_size,
                              hipStream_t stream) {
    const float* emb = (const float*)d_in[0];
    const float* W1  = (const float*)d_in[1];
    const float* b1  = (const float*)d_in[2];
    const float* W2  = (const float*)d_in[3];
    const float* b2  = (const float*)d_in[4];
    const int* ids   = (const int*)d_in[5];
    const int* esrc  = (const int*)d_in[6];
    const int* edst  = (const int*)d_in[7];
    float* out = (float*)d_out;

    // workspace layout (~42 MB)
    ushort_t* h0b = (ushort_t*)d_ws;                    // [N][128] bf16, 12.8 MB
    ushort_t* a1b = h0b + (size_t)N_NODES * 128;        // [N][128] bf16, 12.8 MB
    ushort_t* gb  = a1b + (size_t)N_NODES * 128;        // [N][128] bf16, 12.8 MB
    ushort_t* W1t = gb + (size_t)N_NODES * 128;         // [208][128] bf16
    ushort_t* W2t = W1t + 208 * 128;                    // [112][256] bf16
    int* deg    = (int*)(W2t + 112 * 256);
    int* off    = deg + N_NODES;
    int* cursor = off + (N_NODES + 1);
    int* ssrc   = cursor + N_NODES;                     // 800K ints

    // CSR build (reused by both layers)
    hipMemsetAsync(deg, 0, N_NODES * sizeof(int), stream);
    count_deg<<<(N_EDGES + 255) / 256, 256, 0, stream>>>(edst, deg);
    scan_deg<<<1, 1024, 0, stream>>>(deg, off, cursor);

    // scatter + gather + weight-prep (mutually independent) in one launch
    scatter_gather_prep<<<9591, 256, 0, stream>>>(esrc, edst, cursor, ssrc,
                                                  (const float4*)emb, ids, (uint2*)h0b,
                                                  W1, W2, W1t, W2t);

    // agg1 = segsum(h0[src])  (bf16 pitch-256B out)
    agg_bf16<false><<<N_NODES / 4, 256, 0, stream>>>((const unsigned*)h0b, ssrc, off,
                                                     nullptr, (unsigned*)a1b, nullptr);
    // g = relu(agg1 @ W1 + b1) @ W2  (h1 never leaves LDS)
    gemm_fused<<<(N_NODES + 63) / 64, 256, 0, stream>>>(a1b, W1t, b1, W2t, gb);
    // out = relu(segsum(g[src]) + b2)  (fp32 out)
    agg_bf16<true><<<N_NODES / 4, 256, 0, stream>>>((const unsigned*)gb, ssrc, off,
                                                    b2, nullptr, (float2*)out);
}